// Round 15
// baseline (200.579 us; speedup 1.0000x reference)
//
#include <hip/hip_runtime.h>

// WaveNet fused kernel for MI355X (gfx950).
// L=10 layers of pointwise convs (C=128), B=4, T=32768.
// R15: cross-block overlap. LDS law learned: per-WG static limit = 128 KiB
// (hard, silent launch fail), per-CU residency pool = 160 KiB (R1 evidence:
// 66.5KB blocks -> 2 resident). R14's 128KiB block = 1 block/CU, so all 8
// waves stall together at each barrier. R15: 4-wave/256-thread blocks at
// exactly 64KB (act 32K + wst 32K; s_wr dropped, Wr direct-global RAW like
// verified R6) -> 2 blocks/CU, 2 waves/SIMD from DIFFERENT blocks: barrier
// stalls and Wr L2 latency hidden by the other block. R14's lean body
// (B-first GEMM2/3, hv-bridge exchange) kept verbatim. (256,2), grid 1024.

typedef __bf16 bf16x8 __attribute__((ext_vector_type(8)));
typedef float  f32x4  __attribute__((ext_vector_type(4)));
typedef unsigned int uint;
typedef unsigned long long u64;
typedef unsigned short u16;

#define MFMA16(a, b, c) __builtin_amdgcn_mfma_f32_16x16x32_bf16((a), (b), (c), 0, 0, 0)

__device__ __forceinline__ u16 f2bf(float f) {
    uint u = __float_as_uint(f);
    u += 0x7fffu + ((u >> 16) & 1u);   // RNE
    return (u16)(u >> 16);
}
__device__ __forceinline__ float bf2f(u16 s) {
    return __uint_as_float(((uint)s) << 16);
}
__device__ __forceinline__ u64 pack4(f32x4 v) {
    uint a, b;
    asm("v_cvt_pk_bf16_f32 %0, %1, %2" : "=v"(a) : "v"(v[0]), "v"(v[1]));
    asm("v_cvt_pk_bf16_f32 %0, %1, %2" : "=v"(b) : "v"(v[2]), "v"(v[3]));
    return ((u64)b << 32) | (u64)a;
}

// ---------------------------------------------------------------------------
// Weight conversion: fp32 -> bf16 into d_ws.
// Slots (16384 bf16): 0..9 Wd (swz), 10..19 Wr (RAW -- direct global reads),
// 20..29 Ws (swz), 30 Wf1 (swz), 31 Wf2 (swz).
// Swizzle: image byte a (row r=a>>8) holds W[r][(off ^ ((r&7)<<4))>>1] so a
// LINEAR global_load_lds copy yields the bank-conflict-free LDS layout.
// ---------------------------------------------------------------------------
__global__ void convert_weights(const float* __restrict__ Wd,
                                const float* __restrict__ Wr,
                                const float* __restrict__ Ws,
                                const float* __restrict__ Wf1,
                                const float* __restrict__ Wf2,
                                u16* __restrict__ wsb) {
    int idx = blockIdx.x * 256 + threadIdx.x;
    if (idx >= 32 * 16384) return;
    int slot = idx >> 14;
    int a2   = idx & 16383;
    int r    = a2 >> 7;     // row (output channel)
    int c    = a2 & 127;    // bf16 column index within row
    const float* src;
    bool swz = true;
    if (slot < 10)       { src = Wd  + slot * 16384; }
    else if (slot < 20)  { src = Wr  + (slot - 10) * 16384; swz = false; }
    else if (slot < 30)  { src = Ws  + (slot - 20) * 16384; }
    else if (slot == 30) { src = Wf1; }
    else                 { src = Wf2; }
    int cs = swz ? (c ^ ((r & 7) << 3)) : c;
    wsb[idx] = f2bf(src[r * 128 + cs]);
}

// ---------------------------------------------------------------------------
// Main fused kernel. Grid: 1024 blocks (4 batches * 256 tiles), 256 threads
// (4 waves = 2x2 grid, each wave a 64x64 tile).
// LDS: s_act 32KB = Act[col 128][chan 128] bf16, byte ^= (col&7)<<4 swizzle
//      s_wst 32KB = staged Wd/Ws/Wf (pre-swizzled image, linear copy)
//      total exactly 65536 B -> 2 blocks/CU (<=160KB pool).
// ---------------------------------------------------------------------------
__device__ __forceinline__ void stage_w(const u16* __restrict__ gsrc,
                                        unsigned char* lds, int woff, int wid) {
    // copy 32768 bytes linearly; 4 waves x 8 chunks of 1KB
#pragma unroll
    for (int i = 0; i < 8; ++i) {
        const u16* g = gsrc + woff + i * 512;
        __builtin_amdgcn_global_load_lds(
            (const __attribute__((address_space(1))) uint*)g,
            (__attribute__((address_space(3))) uint*)(lds + wid * 8192 + i * 1024),
            16, 0, 0);
    }
}

__global__ __launch_bounds__(256, 2)
void wavenet_main(const float* __restrict__ x,
                  const u16* __restrict__ wsb,
                  const float* __restrict__ bd,
                  const float* __restrict__ br,
                  const float* __restrict__ bs,
                  const float* __restrict__ bf1,
                  const float* __restrict__ bf2,
                  float* __restrict__ partial) {
    __shared__ __align__(16) unsigned char s_act[32768];
    __shared__ __align__(16) unsigned char s_wst[32768];

    const int tid  = threadIdx.x;
    const int lane = tid & 63;
    const int wid  = tid >> 6;      // 0..3
    const int wr   = wid >> 1;      // wave row (0..1): rows wr*64..+63
    const int wc   = wid & 1;       // wave col (0..1): cols wc*64..+63
    const int lo   = lane & 15;
    const int hi   = lane >> 4;

    // precomputed swizzled LDS base offsets (thread-constant):
    //   A-frag (weights):  s_wst + bW[ks] + m*4096
    //   B-frag (act):      s_act + bB[ks] + n*4096
    //   exchange rows:     s_act + bX[m]  + n*4096   (hv read / out,h write)
    const int xc = (lo & 7) << 4;
    int bW[4], bB[4], bX[4];
#pragma unroll
    for (int ks = 0; ks < 4; ++ks) {
        int kk = ((ks << 6) + (hi << 4)) ^ xc;
        bW[ks] = (wr * 64 + lo) * 256 + kk;
        bB[ks] = (wc * 64 + lo) * 256 + kk;
    }
#pragma unroll
    for (int m = 0; m < 4; ++m)
        bX[m] = (wc * 64 + lo) * 256 + ((wr * 128 + m * 32 + hi * 8) ^ xc);

    const int woff = wid * 4096 + lane * 8;   // stage_w per-thread src offset

    const int blk = blockIdx.x;
    const int b   = blk >> 8;               // 256 tiles per batch
    const int t0  = (blk & 255) * 128;

    // ---- issue stage of Wd_0 (async), then stage x tile into s_act --------
    stage_w(wsb + 0 * 16384, s_wst, woff, wid);

    {
        const float* xb = x + (size_t)b * (128u * 32768u) + t0;
#pragma unroll
        for (int i = 0; i < 16; ++i) {
            int task = wid * 16 + i;        // 64 tasks: 32 chan-groups x 2 t-chunks
            int tc = task & 1;
            int cg = task >> 1;
            int t  = tc * 64 + lane;        // col in tile (0..127)
            int c0 = cg * 4;
            f32x4 v;
            v[0] = xb[(c0 + 0) * 32768 + t];
            v[1] = xb[(c0 + 1) * 32768 + t];
            v[2] = xb[(c0 + 2) * 32768 + t];
            v[3] = xb[(c0 + 3) * 32768 + t];
            int byte = t * 256 + ((c0 * 2) ^ ((t & 7) << 4));
            *(u64*)(s_act + byte) = pack4(v);
        }
    }

    // skip accumulator (fp32, persistent across layers)
    f32x4 sk[4][4];
#pragma unroll
    for (int m = 0; m < 4; ++m)
#pragma unroll
        for (int n = 0; n < 4; ++n) { f32x4 z = {0.f, 0.f, 0.f, 0.f}; sk[m][n] = z; }

    __syncthreads();    // x staged, Wd0 ready (barrier drains vmcnt+lgkmcnt)

    f32x4 h_acc[4][4];

#pragma unroll 1
    for (int l = 0; l < 10; ++l) {
        // --- GEMM1: out = Wd . h + bd  (A = s_wst, B = s_act) -------------
        f32x4 bdv[4];
#pragma unroll
        for (int m = 0; m < 4; ++m)
            bdv[m] = *(const f32x4*)(bd + l * 128 + wr * 64 + m * 16 + hi * 4);

        f32x4 out[4][4];
#pragma unroll
        for (int m = 0; m < 4; ++m)
#pragma unroll
            for (int n = 0; n < 4; ++n) out[m][n] = bdv[m];

#pragma unroll
        for (int ks = 0; ks < 4; ++ks) {
            bf16x8 A[4];
#pragma unroll
            for (int m = 0; m < 4; ++m) A[m] = *(const bf16x8*)(s_wst + bW[ks] + m * 4096);
#pragma unroll
            for (int n = 0; n < 4; ++n) {
                bf16x8 B = *(const bf16x8*)(s_act + bB[ks] + n * 4096);
#pragma unroll
                for (int m = 0; m < 4; ++m) out[m][n] = MFMA16(A[m], B, out[m][n]);
            }
        }
        __syncthreads();                        // all reads of h & Wd done

        // issue stage of Ws_l over Wd (reads completed at barrier)
        stage_w(wsb + (20 + l) * 16384, s_wst, woff, wid);

        // read h (C-init for residual GEMM) from own region, then overwrite
        // with out (bf16, bias already folded in).  [R11 known-good form]
        u64 hv[4][4];
#pragma unroll
        for (int m = 0; m < 4; ++m)
#pragma unroll
            for (int n = 0; n < 4; ++n)
                hv[m][n] = *(const u64*)(s_act + bX[m] + n * 4096);
        asm volatile("" ::: "memory");          // keep reads before writes
#pragma unroll
        for (int m = 0; m < 4; ++m)
#pragma unroll
            for (int n = 0; n < 4; ++n)
                *(u64*)(s_act + bX[m] + n * 4096) = pack4(out[m][n]);
#pragma unroll
        for (int m = 0; m < 4; ++m)
#pragma unroll
            for (int n = 0; n < 4; ++n) {
                f32x4 h;
                h[0] = bf2f((u16)(hv[m][n]      ));
                h[1] = bf2f((u16)(hv[m][n] >> 16));
                h[2] = bf2f((u16)(hv[m][n] >> 32));
                h[3] = bf2f((u16)(hv[m][n] >> 48));
                h_acc[m][n] = h;
            }
        __syncthreads();                        // out visible, Ws staged

        // --- paired GEMM2/3: sk += Ws.out ; h_acc += Wr.out (B shared) ----
        // Aw from s_wst (LDS), Ar direct from global (RAW layout, L2-resident;
        // latency hidden by the co-resident second block).
        const u16* wrp = wsb + (10 + l) * 16384;
#pragma unroll
        for (int ks = 0; ks < 4; ++ks) {
            bf16x8 B[4];
#pragma unroll
            for (int n = 0; n < 4; ++n) B[n] = *(const bf16x8*)(s_act + bB[ks] + n * 4096);
#pragma unroll
            for (int m = 0; m < 4; ++m) {
                bf16x8 Aw = *(const bf16x8*)(s_wst + bW[ks] + m * 4096);
                bf16x8 Ar = *(const bf16x8*)(wrp + (wr * 64 + m * 16 + lo) * 128 + ks * 32 + hi * 8);
#pragma unroll
                for (int n = 0; n < 4; ++n) {
                    sk[m][n]    = MFMA16(Aw, B[n], sk[m][n]);
                    h_acc[m][n] = MFMA16(Ar, B[n], h_acc[m][n]);
                }
            }
        }
        // per-layer biases: skip += bs, h += br
#pragma unroll
        for (int m = 0; m < 4; ++m) {
            f32x4 bsv = *(const f32x4*)(bs + l * 128 + wr * 64 + m * 16 + hi * 4);
            f32x4 brv = *(const f32x4*)(br + l * 128 + wr * 64 + m * 16 + hi * 4);
#pragma unroll
            for (int n = 0; n < 4; ++n) { sk[m][n] += bsv; h_acc[m][n] += brv; }
        }
        __syncthreads();                        // Ws & out reads done

        if (l < 9) {
            stage_w(wsb + (l + 1) * 16384, s_wst, woff, wid);   // Wd_{l+1}
            // write h (bf16) back to act
#pragma unroll
            for (int m = 0; m < 4; ++m)
#pragma unroll
                for (int n = 0; n < 4; ++n)
                    *(u64*)(s_act + bX[m] + n * 4096) = pack4(h_acc[m][n]);
            __syncthreads();                    // h visible, Wd ready
        }
    }

    // ---- final conv head --------------------------------------------------
    // act currently holds out_9 (reads all done). Write relu(skip) into act.
    stage_w(wsb + 30 * 16384, s_wst, woff, wid);       // Wf1
#pragma unroll
    for (int m = 0; m < 4; ++m)
#pragma unroll
        for (int n = 0; n < 4; ++n) {
            f32x4 v;
#pragma unroll
            for (int r = 0; r < 4; ++r) v[r] = fmaxf(sk[m][n][r], 0.f);
            *(u64*)(s_act + bX[m] + n * 4096) = pack4(v);
        }
    __syncthreads();

    // GEMM f1: g1 = relu(Wf1 . rs + bf1)
    f32x4 g1[4][4];
#pragma unroll
    for (int m = 0; m < 4; ++m) {
        f32x4 bv = *(const f32x4*)(bf1 + wr * 64 + m * 16 + hi * 4);
#pragma unroll
        for (int n = 0; n < 4; ++n) g1[m][n] = bv;
    }
#pragma unroll
    for (int ks = 0; ks < 4; ++ks) {
        bf16x8 A[4];
#pragma unroll
        for (int m = 0; m < 4; ++m) A[m] = *(const bf16x8*)(s_wst + bW[ks] + m * 4096);
#pragma unroll
        for (int n = 0; n < 4; ++n) {
            bf16x8 B = *(const bf16x8*)(s_act + bB[ks] + n * 4096);
#pragma unroll
            for (int m = 0; m < 4; ++m) g1[m][n] = MFMA16(A[m], B, g1[m][n]);
        }
    }
    __syncthreads();                            // reads done

    stage_w(wsb + 31 * 16384, s_wst, woff, wid);       // Wf2
#pragma unroll
    for (int m = 0; m < 4; ++m)
#pragma unroll
        for (int n = 0; n < 4; ++n) {
            f32x4 v;
#pragma unroll
            for (int r = 0; r < 4; ++r) v[r] = fmaxf(g1[m][n][r], 0.f);
            *(u64*)(s_act + bX[m] + n * 4096) = pack4(v);
        }
    __syncthreads();

    // GEMM f2: g2 = Wf2 . g1 + bf2
    f32x4 g2[4][4];
#pragma unroll
    for (int m = 0; m < 4; ++m) {
        f32x4 bv = *(const f32x4*)(bf2 + wr * 64 + m * 16 + hi * 4);
#pragma unroll
        for (int n = 0; n < 4; ++n) g2[m][n] = bv;
    }
#pragma unroll
    for (int ks = 0; ks < 4; ++ks) {
        bf16x8 A[4];
#pragma unroll
        for (int m = 0; m < 4; ++m) A[m] = *(const bf16x8*)(s_wst + bW[ks] + m * 4096);
#pragma unroll
        for (int n = 0; n < 4; ++n) {
            bf16x8 B = *(const bf16x8*)(s_act + bB[ks] + n * 4096);
#pragma unroll
            for (int m = 0; m < 4; ++m) g2[m][n] = MFMA16(A[m], B, g2[m][n]);
        }
    }

    // ---- column reduction: per-wave sums straight to global partials -----
    // partial layout: [blk][wc][128] floats
    f32x4 s[4];
#pragma unroll
    for (int m = 0; m < 4; ++m) {
        s[m] = g2[m][0];
#pragma unroll
        for (int n = 1; n < 4; ++n) s[m] += g2[m][n];
    }
#pragma unroll
    for (int m = 0; m < 4; ++m)
#pragma unroll
        for (int r = 0; r < 4; ++r) {
            float v = s[m][r];
            v += __shfl_xor(v, 1, 16);
            v += __shfl_xor(v, 2, 16);
            v += __shfl_xor(v, 4, 16);
            v += __shfl_xor(v, 8, 16);
            s[m][r] = v;
        }
    if (lo == 0) {
        float* pw = partial + ((size_t)(blk * 2 + wc)) * 128;
#pragma unroll
        for (int m = 0; m < 4; ++m)
#pragma unroll
            for (int r = 0; r < 4; ++r)
                pw[wr * 64 + m * 16 + hi * 4 + r] = s[m][r];
    }
}

// ---------------------------------------------------------------------------
// Deterministic final reduce:
// out[b][c] = (1/T) * sum_{tile 0..255, w 0..1} partial[((b*256+tile)*2+w)*128+c]
// Grid: 512 blocks (b*128+c) x 64 lanes.
// ---------------------------------------------------------------------------
__global__ void reduce_partials(const float* __restrict__ partial,
                                float* __restrict__ out) {
    int bc = blockIdx.x;             // 0..511
    int b  = bc >> 7, c = bc & 127;
    int lane = threadIdx.x;          // 0..63
    float s = 0.f;
#pragma unroll
    for (int i = 0; i < 4; ++i) {
        int tile = lane + 64 * i;
        int base = ((b * 256 + tile) * 2) * 128 + c;
        s += partial[base] + partial[base + 128];
    }
    s += __shfl_xor(s, 32);
    s += __shfl_xor(s, 16);
    s += __shfl_xor(s, 8);
    s += __shfl_xor(s, 4);
    s += __shfl_xor(s, 2);
    s += __shfl_xor(s, 1);
    if (lane == 0) out[b * 128 + c] = s * (1.0f / 32768.0f);
}

extern "C" void kernel_launch(void* const* d_in, const int* in_sizes, int n_in,
                              void* d_out, int out_size, void* d_ws, size_t ws_size,
                              hipStream_t stream) {
    const float* x   = (const float*)d_in[0];
    const float* Wd  = (const float*)d_in[1];
    const float* bd  = (const float*)d_in[2];
    const float* Wr  = (const float*)d_in[3];
    const float* br  = (const float*)d_in[4];
    const float* Ws  = (const float*)d_in[5];
    const float* bs  = (const float*)d_in[6];
    const float* Wf1 = (const float*)d_in[7];
    const float* bf1 = (const float*)d_in[8];
    const float* Wf2 = (const float*)d_in[9];
    const float* bf2 = (const float*)d_in[10];

    u16*   wsb     = (u16*)d_ws;                                  // 1 MB bf16 weights
    float* partial = (float*)((char*)d_ws + 32 * 16384 * 2);      // 1 MB partials

    convert_weights<<<2048, 256, 0, stream>>>(Wd, Wr, Ws, Wf1, Wf2, wsb);
    wavenet_main<<<1024, 256, 0, stream>>>(x, wsb, bd, br, bs, bf1, bf2, partial);
    reduce_partials<<<512, 64, 0, stream>>>(partial, (float*)d_out);
}

// Round 17
// 181.254 us; speedup vs baseline: 1.1066x; 1.1066x over previous
//
#include <hip/hip_runtime.h>

// WaveNet fused kernel for MI355X (gfx950).
// L=10 layers of pointwise convs (C=128), B=4, T=32768.
// R17 = R14 EXACT (verified 167us: 8-wave 128x256 block, 64x64 wave tiles,
// Wd/Ws in s_wst + Wr in s_wr both LDS-staged, hv-bridged exchange,
// LDS=131072B, (512,1), B-first GEMM2/3) + s_setprio(1)/(0) around the
// main-loop MFMA clusters (T5): R14's 2 waves/SIMD have staging-vs-MFMA
// phase diversity, so the CU scheduler can favor the MFMA-issuing wave.
// R15 (Wr direct-global, 2 blk/CU) and R16 (time-muxed weight buffer,
// GEMM2/3 split) both failed -- sync-structure exploration frozen.

typedef __bf16 bf16x8 __attribute__((ext_vector_type(8)));
typedef float  f32x4  __attribute__((ext_vector_type(4)));
typedef unsigned int uint;
typedef unsigned long long u64;
typedef unsigned short u16;

#define MFMA16(a, b, c) __builtin_amdgcn_mfma_f32_16x16x32_bf16((a), (b), (c), 0, 0, 0)

__device__ __forceinline__ u16 f2bf(float f) {
    uint u = __float_as_uint(f);
    u += 0x7fffu + ((u >> 16) & 1u);   // RNE
    return (u16)(u >> 16);
}
__device__ __forceinline__ float bf2f(u16 s) {
    return __uint_as_float(((uint)s) << 16);
}
__device__ __forceinline__ u64 pack4(f32x4 v) {
    uint a, b;
    asm("v_cvt_pk_bf16_f32 %0, %1, %2" : "=v"(a) : "v"(v[0]), "v"(v[1]));
    asm("v_cvt_pk_bf16_f32 %0, %1, %2" : "=v"(b) : "v"(v[2]), "v"(v[3]));
    return ((u64)b << 32) | (u64)a;
}

// ---------------------------------------------------------------------------
// Weight conversion: fp32 -> bf16 into d_ws, ALL slots pre-swizzled for the
// LDS image (linear global_load_lds copy yields the conflict-free layout).
// Slots (16384 bf16): 0..9 Wd, 10..19 Wr, 20..29 Ws, 30 Wf1, 31 Wf2.
// ---------------------------------------------------------------------------
__global__ void convert_weights(const float* __restrict__ Wd,
                                const float* __restrict__ Wr,
                                const float* __restrict__ Ws,
                                const float* __restrict__ Wf1,
                                const float* __restrict__ Wf2,
                                u16* __restrict__ wsb) {
    int idx = blockIdx.x * 256 + threadIdx.x;
    if (idx >= 32 * 16384) return;
    int slot = idx >> 14;
    int a2   = idx & 16383;
    int r    = a2 >> 7;     // row (output channel)
    int c    = a2 & 127;    // bf16 column index within row
    const float* src;
    if (slot < 10)       { src = Wd  + slot * 16384; }
    else if (slot < 20)  { src = Wr  + (slot - 10) * 16384; }
    else if (slot < 30)  { src = Ws  + (slot - 20) * 16384; }
    else if (slot == 30) { src = Wf1; }
    else                 { src = Wf2; }
    int cs = c ^ ((r & 7) << 3);
    wsb[idx] = f2bf(src[r * 128 + cs]);
}

// ---------------------------------------------------------------------------
// Main fused kernel. Grid: 512 blocks (4 batches * 128 tiles), 512 threads
// (8 waves = 2 row-groups x 4 col-groups, each wave a 64x64 tile).
// LDS: s_act 64KB = Act[col 256][chan 128] bf16, byte ^= (col&7)<<4 swizzle
//      s_wst 32KB = staged Wd/Ws/Wf (pre-swizzled image, linear copy)
//      s_wr  32KB = staged Wr          -- total exactly 131072 B
// ---------------------------------------------------------------------------
__device__ __forceinline__ void stage_w(const u16* __restrict__ gsrc,
                                        unsigned char* lds, int woff, int wid) {
    // copy 32768 bytes linearly; 8 waves x 4 chunks of 1KB
#pragma unroll
    for (int i = 0; i < 4; ++i) {
        const u16* g = gsrc + woff + i * 512;
        __builtin_amdgcn_global_load_lds(
            (const __attribute__((address_space(1))) uint*)g,
            (__attribute__((address_space(3))) uint*)(lds + wid * 4096 + i * 1024),
            16, 0, 0);
    }
}

__global__ __launch_bounds__(512, 1)
void wavenet_main(const float* __restrict__ x,
                  const u16* __restrict__ wsb,
                  const float* __restrict__ bd,
                  const float* __restrict__ br,
                  const float* __restrict__ bs,
                  const float* __restrict__ bf1,
                  const float* __restrict__ bf2,
                  float* __restrict__ partial) {
    __shared__ __align__(16) unsigned char s_act[65536];
    __shared__ __align__(16) unsigned char s_wst[32768];
    __shared__ __align__(16) unsigned char s_wr[32768];

    const int tid  = threadIdx.x;
    const int lane = tid & 63;
    const int wid  = tid >> 6;      // 0..7
    const int wr   = wid >> 2;      // wave row (0..1): rows wr*64..+63
    const int wc   = wid & 3;       // wave col (0..3): cols wc*64..+63
    const int lo   = lane & 15;
    const int hi   = lane >> 4;

    // precomputed swizzled LDS base offsets (thread-constant):
    //   A-frag (weights):  s_wst/s_wr + bW[ks] + m*4096
    //   B-frag (act):      s_act + bB[ks] + n*4096
    //   exchange rows:     s_act + bX[m]  + n*4096   (hv read / out,h write)
    const int xc = (lo & 7) << 4;
    int bW[4], bB[4], bX[4];
#pragma unroll
    for (int ks = 0; ks < 4; ++ks) {
        int kk = ((ks << 6) + (hi << 4)) ^ xc;
        bW[ks] = (wr * 64 + lo) * 256 + kk;
        bB[ks] = (wc * 64 + lo) * 256 + kk;
    }
#pragma unroll
    for (int m = 0; m < 4; ++m)
        bX[m] = (wc * 64 + lo) * 256 + ((wr * 128 + m * 32 + hi * 8) ^ xc);

    const int woff = wid * 2048 + lane * 8;   // stage_w per-thread src offset

    const int blk = blockIdx.x;
    const int b   = blk >> 7;               // 128 tiles per batch
    const int t0  = (blk & 127) * 256;

    // ---- issue stage of Wd_0 + Wr_0 (async), then stage x tile into s_act --
    stage_w(wsb + 0 * 16384, s_wst, woff, wid);
    stage_w(wsb + 10 * 16384, s_wr, woff, wid);

    {
        const float* xb = x + (size_t)b * (128u * 32768u) + t0;
#pragma unroll
        for (int i = 0; i < 16; ++i) {
            int task = wid * 16 + i;        // 128 tasks: 32 chan-groups x 4 t-chunks
            int tc = task & 3;
            int cg = task >> 2;
            int t  = tc * 64 + lane;        // col in tile (0..255)
            int c0 = cg * 4;
            f32x4 v;
            v[0] = xb[(c0 + 0) * 32768 + t];
            v[1] = xb[(c0 + 1) * 32768 + t];
            v[2] = xb[(c0 + 2) * 32768 + t];
            v[3] = xb[(c0 + 3) * 32768 + t];
            int byte = t * 256 + ((c0 * 2) ^ ((t & 7) << 4));
            *(u64*)(s_act + byte) = pack4(v);
        }
    }

    // skip accumulator (fp32, persistent across layers)
    f32x4 sk[4][4];
#pragma unroll
    for (int m = 0; m < 4; ++m)
#pragma unroll
        for (int n = 0; n < 4; ++n) { f32x4 z = {0.f, 0.f, 0.f, 0.f}; sk[m][n] = z; }

    __syncthreads();    // x staged, Wd0+Wr0 ready (barrier drains vmcnt+lgkmcnt)

    f32x4 h_acc[4][4];

#pragma unroll 1
    for (int l = 0; l < 10; ++l) {
        // --- GEMM1: out = Wd . h + bd  (A = s_wst, B = s_act) -------------
        f32x4 bdv[4];
#pragma unroll
        for (int m = 0; m < 4; ++m)
            bdv[m] = *(const f32x4*)(bd + l * 128 + wr * 64 + m * 16 + hi * 4);

        f32x4 out[4][4];
#pragma unroll
        for (int m = 0; m < 4; ++m)
#pragma unroll
            for (int n = 0; n < 4; ++n) out[m][n] = bdv[m];

        __builtin_amdgcn_s_setprio(1);
#pragma unroll
        for (int ks = 0; ks < 4; ++ks) {
            bf16x8 A[4];
#pragma unroll
            for (int m = 0; m < 4; ++m) A[m] = *(const bf16x8*)(s_wst + bW[ks] + m * 4096);
#pragma unroll
            for (int n = 0; n < 4; ++n) {
                bf16x8 B = *(const bf16x8*)(s_act + bB[ks] + n * 4096);
#pragma unroll
                for (int m = 0; m < 4; ++m) out[m][n] = MFMA16(A[m], B, out[m][n]);
            }
        }
        __builtin_amdgcn_s_setprio(0);
        __syncthreads();                        // all reads of h & Wd done

        // issue stage of Ws_l over Wd (reads completed at barrier)
        stage_w(wsb + (20 + l) * 16384, s_wst, woff, wid);

        // read h (C-init for residual GEMM) from own region, then overwrite
        // with out (bf16, bias already folded in).  [R11 known-good form]
        u64 hv[4][4];
#pragma unroll
        for (int m = 0; m < 4; ++m)
#pragma unroll
            for (int n = 0; n < 4; ++n)
                hv[m][n] = *(const u64*)(s_act + bX[m] + n * 4096);
        asm volatile("" ::: "memory");          // keep reads before writes
#pragma unroll
        for (int m = 0; m < 4; ++m)
#pragma unroll
            for (int n = 0; n < 4; ++n)
                *(u64*)(s_act + bX[m] + n * 4096) = pack4(out[m][n]);
#pragma unroll
        for (int m = 0; m < 4; ++m)
#pragma unroll
            for (int n = 0; n < 4; ++n) {
                f32x4 h;
                h[0] = bf2f((u16)(hv[m][n]      ));
                h[1] = bf2f((u16)(hv[m][n] >> 16));
                h[2] = bf2f((u16)(hv[m][n] >> 32));
                h[3] = bf2f((u16)(hv[m][n] >> 48));
                h_acc[m][n] = h;
            }
        __syncthreads();                        // out visible, Ws staged

        // --- paired GEMM2/3: sk += Ws.out ; h_acc += Wr.out (B shared) ----
        // B[4] loaded once per ks, Aw/Ar per-m (R14 arch-reg trim).
        __builtin_amdgcn_s_setprio(1);
#pragma unroll
        for (int ks = 0; ks < 4; ++ks) {
            bf16x8 B[4];
#pragma unroll
            for (int n = 0; n < 4; ++n) B[n] = *(const bf16x8*)(s_act + bB[ks] + n * 4096);
#pragma unroll
            for (int m = 0; m < 4; ++m) {
                bf16x8 Aw = *(const bf16x8*)(s_wst + bW[ks] + m * 4096);
                bf16x8 Ar = *(const bf16x8*)(s_wr  + bW[ks] + m * 4096);
#pragma unroll
                for (int n = 0; n < 4; ++n) {
                    sk[m][n]    = MFMA16(Aw, B[n], sk[m][n]);
                    h_acc[m][n] = MFMA16(Ar, B[n], h_acc[m][n]);
                }
            }
        }
        __builtin_amdgcn_s_setprio(0);
        // per-layer biases: skip += bs, h += br
#pragma unroll
        for (int m = 0; m < 4; ++m) {
            f32x4 bsv = *(const f32x4*)(bs + l * 128 + wr * 64 + m * 16 + hi * 4);
            f32x4 brv = *(const f32x4*)(br + l * 128 + wr * 64 + m * 16 + hi * 4);
#pragma unroll
            for (int n = 0; n < 4; ++n) { sk[m][n] += bsv; h_acc[m][n] += brv; }
        }
        __syncthreads();                        // Ws, Wr & out reads done

        if (l < 9) {
            stage_w(wsb + (l + 1) * 16384, s_wst, woff, wid);   // Wd_{l+1}
            stage_w(wsb + (11 + l) * 16384, s_wr, woff, wid);   // Wr_{l+1}
            // write h (bf16) back to act
#pragma unroll
            for (int m = 0; m < 4; ++m)
#pragma unroll
                for (int n = 0; n < 4; ++n)
                    *(u64*)(s_act + bX[m] + n * 4096) = pack4(h_acc[m][n]);
            __syncthreads();                    // h visible, Wd+Wr ready
        }
    }

    // ---- final conv head --------------------------------------------------
    // act currently holds out_9 (reads all done). Write relu(skip) into act.
    stage_w(wsb + 30 * 16384, s_wst, woff, wid);       // Wf1
#pragma unroll
    for (int m = 0; m < 4; ++m)
#pragma unroll
        for (int n = 0; n < 4; ++n) {
            f32x4 v;
#pragma unroll
            for (int r = 0; r < 4; ++r) v[r] = fmaxf(sk[m][n][r], 0.f);
            *(u64*)(s_act + bX[m] + n * 4096) = pack4(v);
        }
    __syncthreads();

    // GEMM f1: g1 = relu(Wf1 . rs + bf1)
    f32x4 g1[4][4];
#pragma unroll
    for (int m = 0; m < 4; ++m) {
        f32x4 bv = *(const f32x4*)(bf1 + wr * 64 + m * 16 + hi * 4);
#pragma unroll
        for (int n = 0; n < 4; ++n) g1[m][n] = bv;
    }
#pragma unroll
    for (int ks = 0; ks < 4; ++ks) {
        bf16x8 A[4];
#pragma unroll
        for (int m = 0; m < 4; ++m) A[m] = *(const bf16x8*)(s_wst + bW[ks] + m * 4096);
#pragma unroll
        for (int n = 0; n < 4; ++n) {
            bf16x8 B = *(const bf16x8*)(s_act + bB[ks] + n * 4096);
#pragma unroll
            for (int m = 0; m < 4; ++m) g1[m][n] = MFMA16(A[m], B, g1[m][n]);
        }
    }
    __syncthreads();                            // reads done

    stage_w(wsb + 31 * 16384, s_wst, woff, wid);       // Wf2
#pragma unroll
    for (int m = 0; m < 4; ++m)
#pragma unroll
        for (int n = 0; n < 4; ++n) {
            f32x4 v;
#pragma unroll
            for (int r = 0; r < 4; ++r) v[r] = fmaxf(g1[m][n][r], 0.f);
            *(u64*)(s_act + bX[m] + n * 4096) = pack4(v);
        }
    __syncthreads();

    // GEMM f2: g2 = Wf2 . g1 + bf2
    f32x4 g2[4][4];
#pragma unroll
    for (int m = 0; m < 4; ++m) {
        f32x4 bv = *(const f32x4*)(bf2 + wr * 64 + m * 16 + hi * 4);
#pragma unroll
        for (int n = 0; n < 4; ++n) g2[m][n] = bv;
    }
#pragma unroll
    for (int ks = 0; ks < 4; ++ks) {
        bf16x8 A[4];
#pragma unroll
        for (int m = 0; m < 4; ++m) A[m] = *(const bf16x8*)(s_wst + bW[ks] + m * 4096);
#pragma unroll
        for (int n = 0; n < 4; ++n) {
            bf16x8 B = *(const bf16x8*)(s_act + bB[ks] + n * 4096);
#pragma unroll
            for (int m = 0; m < 4; ++m) g2[m][n] = MFMA16(A[m], B, g2[m][n]);
        }
    }

    // ---- column reduction: per-wave sums straight to global partials -----
    // partial layout: [blk][wc][128] floats
    f32x4 s[4];
#pragma unroll
    for (int m = 0; m < 4; ++m) {
        s[m] = g2[m][0];
#pragma unroll
        for (int n = 1; n < 4; ++n) s[m] += g2[m][n];
    }
#pragma unroll
    for (int m = 0; m < 4; ++m)
#pragma unroll
        for (int r = 0; r < 4; ++r) {
            float v = s[m][r];
            v += __shfl_xor(v, 1, 16);
            v += __shfl_xor(v, 2, 16);
            v += __shfl_xor(v, 4, 16);
            v += __shfl_xor(v, 8, 16);
            s[m][r] = v;
        }
    if (lo == 0) {
        float* pw = partial + ((size_t)(blk * 4 + wc)) * 128;
#pragma unroll
        for (int m = 0; m < 4; ++m)
#pragma unroll
            for (int r = 0; r < 4; ++r)
                pw[wr * 64 + m * 16 + hi * 4 + r] = s[m][r];
    }
}

// ---------------------------------------------------------------------------
// Deterministic final reduce:
// out[b][c] = (1/T) * sum_{tile 0..127, w 0..3} partial[((b*128+tile)*4+w)*128+c]
// Grid: 512 blocks (b*128+c) x 64 lanes.
// ---------------------------------------------------------------------------
__global__ void reduce_partials(const float* __restrict__ partial,
                                float* __restrict__ out) {
    int bc = blockIdx.x;             // 0..511
    int b  = bc >> 7, c = bc & 127;
    int lane = threadIdx.x;          // 0..63
    float s = 0.f;
#pragma unroll
    for (int i = 0; i < 2; ++i) {
        int tile = lane + 64 * i;
        int base = ((b * 128 + tile) * 4) * 128 + c;
        s += partial[base] + partial[base + 128] +
             partial[base + 256] + partial[base + 384];
    }
    s += __shfl_xor(s, 32);
    s += __shfl_xor(s, 16);
    s += __shfl_xor(s, 8);
    s += __shfl_xor(s, 4);
    s += __shfl_xor(s, 2);
    s += __shfl_xor(s, 1);
    if (lane == 0) out[b * 128 + c] = s * (1.0f / 32768.0f);
}

extern "C" void kernel_launch(void* const* d_in, const int* in_sizes, int n_in,
                              void* d_out, int out_size, void* d_ws, size_t ws_size,
                              hipStream_t stream) {
    const float* x   = (const float*)d_in[0];
    const float* Wd  = (const float*)d_in[1];
    const float* bd  = (const float*)d_in[2];
    const float* Wr  = (const float*)d_in[3];
    const float* br  = (const float*)d_in[4];
    const float* Ws  = (const float*)d_in[5];
    const float* bs  = (const float*)d_in[6];
    const float* Wf1 = (const float*)d_in[7];
    const float* bf1 = (const float*)d_in[8];
    const float* Wf2 = (const float*)d_in[9];
    const float* bf2 = (const float*)d_in[10];

    u16*   wsb     = (u16*)d_ws;                                  // 1 MB bf16 weights
    float* partial = (float*)((char*)d_ws + 32 * 16384 * 2);      // 1 MB partials

    convert_weights<<<2048, 256, 0, stream>>>(Wd, Wr, Ws, Wf1, Wf2, wsb);
    wavenet_main<<<512, 512, 0, stream>>>(x, wsb, bd, br, bs, bf1, bf2, partial);
    reduce_partials<<<512, 64, 0, stream>>>(partial, (float*)d_out);
}

// Round 19
// 167.768 us; speedup vs baseline: 1.1956x; 1.0804x over previous
//
#include <hip/hip_runtime.h>

// WaveNet fused kernel for MI355X (gfx950).
// L=10 layers of pointwise convs (C=128), B=4, T=32768.
// R19 = R14 EXACT restoration (verified best: 167us bench / 177 in-kernel).
// Structure: 512-thread / 8-wave blocks (2x4 wave grid, 64x64 wave tiles per
// 128x256 block tile), Wd/Ws staged in s_wst + Wr in s_wr via global_load_lds
// (pre-swizzled images, linear copy), hv-bridged h<->out exchange (R11 form --
// FROZEN: all four variants R12/R13/R16/R18 failed), B-first GEMM2/3 register
// trim, LDS = exactly 131072 B, __launch_bounds__(512,1), grid 512.
// Falsified levers: setprio (R17 -8%), Wr direct-global + 2blk/CU (R15 -26%),
// register-h (R13 inf), exchange fusion/split (R12/R18), weight time-mux
// (R16 inf), launch-bounds occupancy games (R2/R7/R10/R11).

typedef __bf16 bf16x8 __attribute__((ext_vector_type(8)));
typedef float  f32x4  __attribute__((ext_vector_type(4)));
typedef unsigned int uint;
typedef unsigned long long u64;
typedef unsigned short u16;

#define MFMA16(a, b, c) __builtin_amdgcn_mfma_f32_16x16x32_bf16((a), (b), (c), 0, 0, 0)

__device__ __forceinline__ u16 f2bf(float f) {
    uint u = __float_as_uint(f);
    u += 0x7fffu + ((u >> 16) & 1u);   // RNE
    return (u16)(u >> 16);
}
__device__ __forceinline__ float bf2f(u16 s) {
    return __uint_as_float(((uint)s) << 16);
}
__device__ __forceinline__ u64 pack4(f32x4 v) {
    uint a, b;
    asm("v_cvt_pk_bf16_f32 %0, %1, %2" : "=v"(a) : "v"(v[0]), "v"(v[1]));
    asm("v_cvt_pk_bf16_f32 %0, %1, %2" : "=v"(b) : "v"(v[2]), "v"(v[3]));
    return ((u64)b << 32) | (u64)a;
}

// ---------------------------------------------------------------------------
// Weight conversion: fp32 -> bf16 into d_ws, ALL slots pre-swizzled for the
// LDS image (linear global_load_lds copy yields the conflict-free layout).
// Slots (16384 bf16): 0..9 Wd, 10..19 Wr, 20..29 Ws, 30 Wf1, 31 Wf2.
// ---------------------------------------------------------------------------
__global__ void convert_weights(const float* __restrict__ Wd,
                                const float* __restrict__ Wr,
                                const float* __restrict__ Ws,
                                const float* __restrict__ Wf1,
                                const float* __restrict__ Wf2,
                                u16* __restrict__ wsb) {
    int idx = blockIdx.x * 256 + threadIdx.x;
    if (idx >= 32 * 16384) return;
    int slot = idx >> 14;
    int a2   = idx & 16383;
    int r    = a2 >> 7;     // row (output channel)
    int c    = a2 & 127;    // bf16 column index within row
    const float* src;
    if (slot < 10)       { src = Wd  + slot * 16384; }
    else if (slot < 20)  { src = Wr  + (slot - 10) * 16384; }
    else if (slot < 30)  { src = Ws  + (slot - 20) * 16384; }
    else if (slot == 30) { src = Wf1; }
    else                 { src = Wf2; }
    int cs = c ^ ((r & 7) << 3);
    wsb[idx] = f2bf(src[r * 128 + cs]);
}

// ---------------------------------------------------------------------------
// Main fused kernel. Grid: 512 blocks (4 batches * 128 tiles), 512 threads
// (8 waves = 2 row-groups x 4 col-groups, each wave a 64x64 tile).
// LDS: s_act 64KB = Act[col 256][chan 128] bf16, byte ^= (col&7)<<4 swizzle
//      s_wst 32KB = staged Wd/Ws/Wf (pre-swizzled image, linear copy)
//      s_wr  32KB = staged Wr          -- total exactly 131072 B
// ---------------------------------------------------------------------------
__device__ __forceinline__ void stage_w(const u16* __restrict__ gsrc,
                                        unsigned char* lds, int woff, int wid) {
    // copy 32768 bytes linearly; 8 waves x 4 chunks of 1KB
#pragma unroll
    for (int i = 0; i < 4; ++i) {
        const u16* g = gsrc + woff + i * 512;
        __builtin_amdgcn_global_load_lds(
            (const __attribute__((address_space(1))) uint*)g,
            (__attribute__((address_space(3))) uint*)(lds + wid * 4096 + i * 1024),
            16, 0, 0);
    }
}

__global__ __launch_bounds__(512, 1)
void wavenet_main(const float* __restrict__ x,
                  const u16* __restrict__ wsb,
                  const float* __restrict__ bd,
                  const float* __restrict__ br,
                  const float* __restrict__ bs,
                  const float* __restrict__ bf1,
                  const float* __restrict__ bf2,
                  float* __restrict__ partial) {
    __shared__ __align__(16) unsigned char s_act[65536];
    __shared__ __align__(16) unsigned char s_wst[32768];
    __shared__ __align__(16) unsigned char s_wr[32768];

    const int tid  = threadIdx.x;
    const int lane = tid & 63;
    const int wid  = tid >> 6;      // 0..7
    const int wr   = wid >> 2;      // wave row (0..1): rows wr*64..+63
    const int wc   = wid & 3;       // wave col (0..3): cols wc*64..+63
    const int lo   = lane & 15;
    const int hi   = lane >> 4;

    // precomputed swizzled LDS base offsets (thread-constant):
    //   A-frag (weights):  s_wst/s_wr + bW[ks] + m*4096
    //   B-frag (act):      s_act + bB[ks] + n*4096
    //   exchange rows:     s_act + bX[m]  + n*4096   (hv read / out,h write)
    const int xc = (lo & 7) << 4;
    int bW[4], bB[4], bX[4];
#pragma unroll
    for (int ks = 0; ks < 4; ++ks) {
        int kk = ((ks << 6) + (hi << 4)) ^ xc;
        bW[ks] = (wr * 64 + lo) * 256 + kk;
        bB[ks] = (wc * 64 + lo) * 256 + kk;
    }
#pragma unroll
    for (int m = 0; m < 4; ++m)
        bX[m] = (wc * 64 + lo) * 256 + ((wr * 128 + m * 32 + hi * 8) ^ xc);

    const int woff = wid * 2048 + lane * 8;   // stage_w per-thread src offset

    const int blk = blockIdx.x;
    const int b   = blk >> 7;               // 128 tiles per batch
    const int t0  = (blk & 127) * 256;

    // ---- issue stage of Wd_0 + Wr_0 (async), then stage x tile into s_act --
    stage_w(wsb + 0 * 16384, s_wst, woff, wid);
    stage_w(wsb + 10 * 16384, s_wr, woff, wid);

    {
        const float* xb = x + (size_t)b * (128u * 32768u) + t0;
#pragma unroll
        for (int i = 0; i < 16; ++i) {
            int task = wid * 16 + i;        // 128 tasks: 32 chan-groups x 4 t-chunks
            int tc = task & 3;
            int cg = task >> 2;
            int t  = tc * 64 + lane;        // col in tile (0..255)
            int c0 = cg * 4;
            f32x4 v;
            v[0] = xb[(c0 + 0) * 32768 + t];
            v[1] = xb[(c0 + 1) * 32768 + t];
            v[2] = xb[(c0 + 2) * 32768 + t];
            v[3] = xb[(c0 + 3) * 32768 + t];
            int byte = t * 256 + ((c0 * 2) ^ ((t & 7) << 4));
            *(u64*)(s_act + byte) = pack4(v);
        }
    }

    // skip accumulator (fp32, persistent across layers)
    f32x4 sk[4][4];
#pragma unroll
    for (int m = 0; m < 4; ++m)
#pragma unroll
        for (int n = 0; n < 4; ++n) { f32x4 z = {0.f, 0.f, 0.f, 0.f}; sk[m][n] = z; }

    __syncthreads();    // x staged, Wd0+Wr0 ready (barrier drains vmcnt+lgkmcnt)

    f32x4 h_acc[4][4];

#pragma unroll 1
    for (int l = 0; l < 10; ++l) {
        // --- GEMM1: out = Wd . h + bd  (A = s_wst, B = s_act) -------------
        f32x4 bdv[4];
#pragma unroll
        for (int m = 0; m < 4; ++m)
            bdv[m] = *(const f32x4*)(bd + l * 128 + wr * 64 + m * 16 + hi * 4);

        f32x4 out[4][4];
#pragma unroll
        for (int m = 0; m < 4; ++m)
#pragma unroll
            for (int n = 0; n < 4; ++n) out[m][n] = bdv[m];

#pragma unroll
        for (int ks = 0; ks < 4; ++ks) {
            bf16x8 A[4];
#pragma unroll
            for (int m = 0; m < 4; ++m) A[m] = *(const bf16x8*)(s_wst + bW[ks] + m * 4096);
#pragma unroll
            for (int n = 0; n < 4; ++n) {
                bf16x8 B = *(const bf16x8*)(s_act + bB[ks] + n * 4096);
#pragma unroll
                for (int m = 0; m < 4; ++m) out[m][n] = MFMA16(A[m], B, out[m][n]);
            }
        }
        __syncthreads();                        // all reads of h & Wd done

        // issue stage of Ws_l over Wd (reads completed at barrier)
        stage_w(wsb + (20 + l) * 16384, s_wst, woff, wid);

        // read h (C-init for residual GEMM) from own region, then overwrite
        // with out (bf16, bias already folded in).  [R11 known-good form,
        // FROZEN -- do not restructure]
        u64 hv[4][4];
#pragma unroll
        for (int m = 0; m < 4; ++m)
#pragma unroll
            for (int n = 0; n < 4; ++n)
                hv[m][n] = *(const u64*)(s_act + bX[m] + n * 4096);
        asm volatile("" ::: "memory");          // keep reads before writes
#pragma unroll
        for (int m = 0; m < 4; ++m)
#pragma unroll
            for (int n = 0; n < 4; ++n)
                *(u64*)(s_act + bX[m] + n * 4096) = pack4(out[m][n]);
#pragma unroll
        for (int m = 0; m < 4; ++m)
#pragma unroll
            for (int n = 0; n < 4; ++n) {
                f32x4 h;
                h[0] = bf2f((u16)(hv[m][n]      ));
                h[1] = bf2f((u16)(hv[m][n] >> 16));
                h[2] = bf2f((u16)(hv[m][n] >> 32));
                h[3] = bf2f((u16)(hv[m][n] >> 48));
                h_acc[m][n] = h;
            }
        __syncthreads();                        // out visible, Ws staged

        // --- paired GEMM2/3: sk += Ws.out ; h_acc += Wr.out (B shared) ----
        // B[4] loaded once per ks, Aw/Ar per-m (R14 arch-reg trim).
#pragma unroll
        for (int ks = 0; ks < 4; ++ks) {
            bf16x8 B[4];
#pragma unroll
            for (int n = 0; n < 4; ++n) B[n] = *(const bf16x8*)(s_act + bB[ks] + n * 4096);
#pragma unroll
            for (int m = 0; m < 4; ++m) {
                bf16x8 Aw = *(const bf16x8*)(s_wst + bW[ks] + m * 4096);
                bf16x8 Ar = *(const bf16x8*)(s_wr  + bW[ks] + m * 4096);
#pragma unroll
                for (int n = 0; n < 4; ++n) {
                    sk[m][n]    = MFMA16(Aw, B[n], sk[m][n]);
                    h_acc[m][n] = MFMA16(Ar, B[n], h_acc[m][n]);
                }
            }
        }
        // per-layer biases: skip += bs, h += br
#pragma unroll
        for (int m = 0; m < 4; ++m) {
            f32x4 bsv = *(const f32x4*)(bs + l * 128 + wr * 64 + m * 16 + hi * 4);
            f32x4 brv = *(const f32x4*)(br + l * 128 + wr * 64 + m * 16 + hi * 4);
#pragma unroll
            for (int n = 0; n < 4; ++n) { sk[m][n] += bsv; h_acc[m][n] += brv; }
        }
        __syncthreads();                        // Ws, Wr & out reads done

        if (l < 9) {
            stage_w(wsb + (l + 1) * 16384, s_wst, woff, wid);   // Wd_{l+1}
            stage_w(wsb + (11 + l) * 16384, s_wr, woff, wid);   // Wr_{l+1}
            // write h (bf16) back to act
#pragma unroll
            for (int m = 0; m < 4; ++m)
#pragma unroll
                for (int n = 0; n < 4; ++n)
                    *(u64*)(s_act + bX[m] + n * 4096) = pack4(h_acc[m][n]);
            __syncthreads();                    // h visible, Wd+Wr ready
        }
    }

    // ---- final conv head --------------------------------------------------
    // act currently holds out_9 (reads all done). Write relu(skip) into act.
    stage_w(wsb + 30 * 16384, s_wst, woff, wid);       // Wf1
#pragma unroll
    for (int m = 0; m < 4; ++m)
#pragma unroll
        for (int n = 0; n < 4; ++n) {
            f32x4 v;
#pragma unroll
            for (int r = 0; r < 4; ++r) v[r] = fmaxf(sk[m][n][r], 0.f);
            *(u64*)(s_act + bX[m] + n * 4096) = pack4(v);
        }
    __syncthreads();

    // GEMM f1: g1 = relu(Wf1 . rs + bf1)
    f32x4 g1[4][4];
#pragma unroll
    for (int m = 0; m < 4; ++m) {
        f32x4 bv = *(const f32x4*)(bf1 + wr * 64 + m * 16 + hi * 4);
#pragma unroll
        for (int n = 0; n < 4; ++n) g1[m][n] = bv;
    }
#pragma unroll
    for (int ks = 0; ks < 4; ++ks) {
        bf16x8 A[4];
#pragma unroll
        for (int m = 0; m < 4; ++m) A[m] = *(const bf16x8*)(s_wst + bW[ks] + m * 4096);
#pragma unroll
        for (int n = 0; n < 4; ++n) {
            bf16x8 B = *(const bf16x8*)(s_act + bB[ks] + n * 4096);
#pragma unroll
            for (int m = 0; m < 4; ++m) g1[m][n] = MFMA16(A[m], B, g1[m][n]);
        }
    }
    __syncthreads();                            // reads done

    stage_w(wsb + 31 * 16384, s_wst, woff, wid);       // Wf2
#pragma unroll
    for (int m = 0; m < 4; ++m)
#pragma unroll
        for (int n = 0; n < 4; ++n) {
            f32x4 v;
#pragma unroll
            for (int r = 0; r < 4; ++r) v[r] = fmaxf(g1[m][n][r], 0.f);
            *(u64*)(s_act + bX[m] + n * 4096) = pack4(v);
        }
    __syncthreads();

    // GEMM f2: g2 = Wf2 . g1 + bf2
    f32x4 g2[4][4];
#pragma unroll
    for (int m = 0; m < 4; ++m) {
        f32x4 bv = *(const f32x4*)(bf2 + wr * 64 + m * 16 + hi * 4);
#pragma unroll
        for (int n = 0; n < 4; ++n) g2[m][n] = bv;
    }
#pragma unroll
    for (int ks = 0; ks < 4; ++ks) {
        bf16x8 A[4];
#pragma unroll
        for (int m = 0; m < 4; ++m) A[m] = *(const bf16x8*)(s_wst + bW[ks] + m * 4096);
#pragma unroll
        for (int n = 0; n < 4; ++n) {
            bf16x8 B = *(const bf16x8*)(s_act + bB[ks] + n * 4096);
#pragma unroll
            for (int m = 0; m < 4; ++m) g2[m][n] = MFMA16(A[m], B, g2[m][n]);
        }
    }

    // ---- column reduction: per-wave sums straight to global partials -----
    // partial layout: [blk][wc][128] floats
    f32x4 s[4];
#pragma unroll
    for (int m = 0; m < 4; ++m) {
        s[m] = g2[m][0];
#pragma unroll
        for (int n = 1; n < 4; ++n) s[m] += g2[m][n];
    }
#pragma unroll
    for (int m = 0; m < 4; ++m)
#pragma unroll
        for (int r = 0; r < 4; ++r) {
            float v = s[m][r];
            v += __shfl_xor(v, 1, 16);
            v += __shfl_xor(v, 2, 16);
            v += __shfl_xor(v, 4, 16);
            v += __shfl_xor(v, 8, 16);
            s[m][r] = v;
        }
    if (lo == 0) {
        float* pw = partial + ((size_t)(blk * 4 + wc)) * 128;
#pragma unroll
        for (int m = 0; m < 4; ++m)
#pragma unroll
            for (int r = 0; r < 4; ++r)
                pw[wr * 64 + m * 16 + hi * 4 + r] = s[m][r];
    }
}

// ---------------------------------------------------------------------------
// Deterministic final reduce:
// out[b][c] = (1/T) * sum_{tile 0..127, w 0..3} partial[((b*128+tile)*4+w)*128+c]
// Grid: 512 blocks (b*128+c) x 64 lanes.
// ---------------------------------------------------------------------------
__global__ void reduce_partials(const float* __restrict__ partial,
                                float* __restrict__ out) {
    int bc = blockIdx.x;             // 0..511
    int b  = bc >> 7, c = bc & 127;
    int lane = threadIdx.x;          // 0..63
    float s = 0.f;
#pragma unroll
    for (int i = 0; i < 2; ++i) {
        int tile = lane + 64 * i;
        int base = ((b * 128 + tile) * 4) * 128 + c;
        s += partial[base] + partial[base + 128] +
             partial[base + 256] + partial[base + 384];
    }
    s += __shfl_xor(s, 32);
    s += __shfl_xor(s, 16);
    s += __shfl_xor(s, 8);
    s += __shfl_xor(s, 4);
    s += __shfl_xor(s, 2);
    s += __shfl_xor(s, 1);
    if (lane == 0) out[b * 128 + c] = s * (1.0f / 32768.0f);
}

extern "C" void kernel_launch(void* const* d_in, const int* in_sizes, int n_in,
                              void* d_out, int out_size, void* d_ws, size_t ws_size,
                              hipStream_t stream) {
    const float* x   = (const float*)d_in[0];
    const float* Wd  = (const float*)d_in[1];
    const float* bd  = (const float*)d_in[2];
    const float* Wr  = (const float*)d_in[3];
    const float* br  = (const float*)d_in[4];
    const float* Ws  = (const float*)d_in[5];
    const float* bs  = (const float*)d_in[6];
    const float* Wf1 = (const float*)d_in[7];
    const float* bf1 = (const float*)d_in[8];
    const float* Wf2 = (const float*)d_in[9];
    const float* bf2 = (const float*)d_in[10];

    u16*   wsb     = (u16*)d_ws;                                  // 1 MB bf16 weights
    float* partial = (float*)((char*)d_ws + 32 * 16384 * 2);      // 1 MB partials

    convert_weights<<<2048, 256, 0, stream>>>(Wd, Wr, Ws, Wf1, Wf2, wsb);
    wavenet_main<<<512, 512, 0, stream>>>(x, wsb, bd, br, bs, bf1, bf2, partial);
    reduce_partials<<<512, 64, 0, stream>>>(partial, (float*)d_out);
}